// Round 6
// baseline (763.773 us; speedup 1.0000x reference)
//
#include <hip/hip_runtime.h>
#include <hip/hip_bf16.h>

// CensorNet T=512,B=256,I=128,H=256 GRU scan + BCE decode.
// R6: 32 rec WGs x 8 batch rows (MFMA per-CU issue is invariant at ~192
// insts/step for ANY WG count -> use the config that minimizes VALU+LDS and
// frees 224 CUs for the fused gi-GEMM role, blocks 32+). Per-wave LDS
// transpose redistributes 8x32 gate elems to 4/lane; slim exp2/rcp gates
// (no clamps: |h|<1 structurally); conflict-tuned strides (xbuf 20/164
// words, hb 272 B); gi as coalesced dwordx2/lane.

typedef __bf16 bf16x8_t __attribute__((ext_vector_type(8)));
typedef float floatx4_t __attribute__((ext_vector_type(4)));
typedef int intx4_t __attribute__((ext_vector_type(4)));
typedef unsigned int u32;
typedef u32 u32x2_t __attribute__((ext_vector_type(2)));

#define SW 2032.0f
#define SH 127.0f
#define INV_S (1.0f / (127.0f * 2032.0f))
#define NL2E (-1.44269504088896f) /* -log2(e) */
#define CRZ (NL2E * INV_S)
#define CN (2.0f * NL2E * INV_S)

static __device__ inline u32 pack2bf(float a, float b) {
  __bf16 x = (__bf16)a, y = (__bf16)b;
  unsigned short ux = *(unsigned short*)&x, uy = *(unsigned short*)&y;
  return (u32)ux | ((u32)uy << 16);
}

// ---------------- prep: quantize W_hh/W_dec to i8, zero h_ws/out ----------
__global__ void prep_kernel(const float* __restrict__ Whh,
                            const float* __restrict__ Wdec,
                            char* __restrict__ Wq, char* __restrict__ wdq,
                            float* __restrict__ h_ws, float* __restrict__ out) {
  int idx = blockIdx.x * 256 + threadIdx.x;  // 65536 total
  for (int i = idx; i < 768 * 256; i += 65536) {
    int v = (int)rintf(Whh[i] * SW);
    v = v > 127 ? 127 : (v < -127 ? -127 : v);
    Wq[i] = (char)v;
  }
  if (idx < 256) {
    int v = (int)rintf(Wdec[idx] * SW);
    v = v > 127 ? 127 : (v < -127 ? -127 : v);
    wdq[idx] = (char)v;
  }
  if (idx < 65536) h_ws[idx] = 0.f;
  if (idx == 0) out[0] = 0.f;
}

// ---------------- fused: rec (blocks 0..31) + gi gemm (blocks 32+) --------
// gi layout, u32x2 units (4 bf16 = cols c..c+3):
//   U = ((t*32 + g)*3 + gate)*512 + w*64 + (cg*8 + row)
// where b = t*256 + g*8 + row, n = gate*256 + w*32 + cg*4 (+0..3).
// Pre-scaled: r,z: NL2E*(gi+bih+bhh); n: 2*NL2E*(gi+bih).
__global__ __launch_bounds__(512) void fused_kernel(
    const char* __restrict__ Wq,    // [768][256] i8
    const char* __restrict__ wdq,   // [256] i8
    const float* __restrict__ x,    // [512*256][128]
    const float* __restrict__ Wih,  // [768][128]
    const float* __restrict__ bih, const float* __restrict__ bhh,
    const float* __restrict__ gt, const float* __restrict__ bdec,
    float* __restrict__ h_ws, float* __restrict__ out,
    const u32x2_t* __restrict__ gir,  // gi for this rec chunk
    u32* __restrict__ giw,            // gi for next chunk (gemm role)
    int t0, int tc, int tg0, int tgc) {
  __shared__ __align__(16) char smem[104448];
  const int tid = threadIdx.x;
  const int w = tid >> 6, lane = tid & 63;
  const int q = lane >> 4, nh = lane & 15;

  if (blockIdx.x < 32) {
    // ================= rec role =================
    if (tc == 0) return;
    const int g = blockIdx.x;       // batch slice: rows g*8..g*8+7
    const int row = lane & 7;       // gate-phase batch row
    const int cg = lane >> 3;       // gate-phase col group (of 4)
    const int colG = w * 32 + cg * 4;
    char* hbp = smem;                        // 2 x [8][272] i8
    int* xb = (int*)(smem + 4352);           // 8 waves x 984 words
    float* logitb = (float*)(smem + 35840);  // tc*8 floats (<=2048 B)

    // W_hh fragments (i8, A-operand): wave w owns cols w*32..+31 per gate
    intx4_t wf[6][4];
#pragma unroll
    for (int c = 0; c < 3; ++c)
#pragma unroll
      for (int ss = 0; ss < 2; ++ss) {
        const int n = c * 256 + w * 32 + ss * 16 + nh;
#pragma unroll
        for (int kb = 0; kb < 4; ++kb)
          wf[c * 2 + ss][kb] =
              *(const intx4_t*)(Wq + (size_t)n * 256 + kb * 64 + q * 16);
      }
    intx4_t wdf[4];
#pragma unroll
    for (int kb = 0; kb < 4; ++kb) {
      intx4_t z = {0, 0, 0, 0};
      intx4_t v = *(const intx4_t*)(wdq + kb * 64 + q * 16);
      wdf[kb] = (nh == 0) ? v : z;  // A-row 0 = Wdec
    }
    const floatx4_t bhv = *(const floatx4_t*)(bhh + 512 + colG);
    floatx4_t bnv;
#pragma unroll
    for (int j = 0; j < 4; ++j) bnv[j] = 2.0f * NL2E * bhv[j];
    const float bdec0 = bdec[0];

    // stage initial h rows 0..7 (quantized i8), one u32 per thread
    {
      const int r = tid >> 6, c0 = (tid & 63) * 4;
      u32 p = 0;
#pragma unroll
      for (int j = 0; j < 4; ++j) {
        int a = (int)rintf(h_ws[(size_t)(g * 8 + r) * 256 + c0 + j] * SH);
        a = a > 127 ? 127 : (a < -127 ? -127 : a);
        p |= ((u32)(a & 255)) << (8 * j);
      }
      *(u32*)(hbp + r * 272 + c0) = p;
    }
    floatx4_t ho = *(const floatx4_t*)(h_ws + (size_t)(g * 8 + row) * 256 +
                                       colG);
    __syncthreads();

    // gi prefetch: 3 x dwordx2 per lane, per-wave 512 B contiguous
    const size_t ub = (size_t)w * 64 + (size_t)(cg * 8 + row);
    u32x2_t gcur[3], gnxt[3];
    {
      const size_t u = (size_t)g * 1536 + ub;
#pragma unroll
      for (int c = 0; c < 3; ++c) gcur[c] = gir[u + c * 512];
    }

#pragma unroll 1
    for (int t = 0; t < tc; ++t) {
      const int pb = t & 1;
      {
        const int tp = (t + 1 < tc) ? t + 1 : t;
        const size_t u = ((size_t)tp * 32 + g) * 1536 + ub;
#pragma unroll
        for (int c = 0; c < 3; ++c) gnxt[c] = gir[u + c * 512];
      }

      intx4_t hbf[4];
#pragma unroll
      for (int kb = 0; kb < 4; ++kb) {
        intx4_t z = {0, 0, 0, 0};
        hbf[kb] = z;
      }
      if (nh < 8) {
#pragma unroll
        for (int kb = 0; kb < 4; ++kb)
          hbf[kb] =
              *(const intx4_t*)(hbp + pb * 2176 + nh * 272 + kb * 64 + q * 16);
      }

      intx4_t acc[6], facc;
#pragma unroll
      for (int cs = 0; cs < 6; ++cs)
#pragma unroll
        for (int j = 0; j < 4; ++j) acc[cs][j] = 0;
#pragma unroll
      for (int j = 0; j < 4; ++j) facc[j] = 0;

#pragma unroll
      for (int kb = 0; kb < 4; ++kb) {
#pragma unroll
        for (int cs = 0; cs < 6; ++cs)
          acc[cs] = __builtin_amdgcn_mfma_i32_16x16x64_i8(wf[cs][kb], hbf[kb],
                                                          acc[cs], 0, 0, 0);
        if (w == 0)
          facc = __builtin_amdgcn_mfma_i32_16x16x64_i8(wdf[kb], hbf[kb], facc,
                                                       0, 0, 0);
      }

      // wave-private transpose: lanes nh<8 scatter j-vectors by (col,row)
      if (nh < 8) {
#pragma unroll
        for (int cs = 0; cs < 6; ++cs)
          *(intx4_t*)&xb[w * 984 + cs * 164 + nh * 20 + q * 4] = acc[cs];
      }
      asm volatile("s_waitcnt lgkmcnt(0)" ::: "memory");
      const int rb = w * 984 + row * 20 + (cg & 3) * 4;
      const int ss = cg >> 2;
      intx4_t aR = *(const intx4_t*)&xb[rb + (0 + ss) * 164];
      intx4_t aZ = *(const intx4_t*)&xb[rb + (2 + ss) * 164];
      intx4_t aN = *(const intx4_t*)&xb[rb + (4 + ss) * 164];

      float gr[4], gz[4], gn[4];
      gr[0] = __uint_as_float(gcur[0].x << 16);
      gr[1] = __uint_as_float(gcur[0].x & 0xffff0000u);
      gr[2] = __uint_as_float(gcur[0].y << 16);
      gr[3] = __uint_as_float(gcur[0].y & 0xffff0000u);
      gz[0] = __uint_as_float(gcur[1].x << 16);
      gz[1] = __uint_as_float(gcur[1].x & 0xffff0000u);
      gz[2] = __uint_as_float(gcur[1].y << 16);
      gz[3] = __uint_as_float(gcur[1].y & 0xffff0000u);
      gn[0] = __uint_as_float(gcur[2].x << 16);
      gn[1] = __uint_as_float(gcur[2].x & 0xffff0000u);
      gn[2] = __uint_as_float(gcur[2].y << 16);
      gn[3] = __uint_as_float(gcur[2].y & 0xffff0000u);

      u32 pk = 0;
#pragma unroll
      for (int j = 0; j < 4; ++j) {
        float rr = __builtin_amdgcn_rcpf(
            1.f +
            __builtin_amdgcn_exp2f(__builtin_fmaf((float)aR[j], CRZ, gr[j])));
        float zz = __builtin_amdgcn_rcpf(
            1.f +
            __builtin_amdgcn_exp2f(__builtin_fmaf((float)aZ[j], CRZ, gz[j])));
        float hn2 = __builtin_fmaf((float)aN[j], CN, bnv[j]);
        float tv =
            2.f * __builtin_amdgcn_rcpf(
                      1.f + __builtin_amdgcn_exp2f(
                                __builtin_fmaf(rr, hn2, gn[j]))) -
            1.f;
        float hnew = tv + zz * (ho[j] - tv);
        ho[j] = hnew;
        int hq = (int)rintf(hnew * SH);  // |h|<1 -> no clamp needed
        pk |= ((u32)(hq & 255)) << (8 * j);
      }
      *(u32*)(hbp + (1 - pb) * 2176 + row * 272 + colG) = pk;

      if (w == 0 && q == 0 && nh < 8 && t >= 1)
        logitb[(t - 1) * 8 + nh] = (float)facc[0] * INV_S + bdec0;
      __syncthreads();
#pragma unroll
      for (int c = 0; c < 3; ++c) gcur[c] = gnxt[c];
    }

    // tail decode of final h
    if (w == 0) {
      intx4_t hbf2[4], fac2;
#pragma unroll
      for (int kb = 0; kb < 4; ++kb) {
        intx4_t z = {0, 0, 0, 0};
        hbf2[kb] = z;
      }
      if (nh < 8) {
#pragma unroll
        for (int kb = 0; kb < 4; ++kb)
          hbf2[kb] = *(const intx4_t*)(hbp + (tc & 1) * 2176 + nh * 272 +
                                       kb * 64 + q * 16);
      }
#pragma unroll
      for (int j = 0; j < 4; ++j) fac2[j] = 0;
#pragma unroll
      for (int kb = 0; kb < 4; ++kb)
        fac2 = __builtin_amdgcn_mfma_i32_16x16x64_i8(wdf[kb], hbf2[kb], fac2,
                                                     0, 0, 0);
      if (q == 0 && nh < 8)
        logitb[(tc - 1) * 8 + nh] = (float)fac2[0] * INV_S + bdec0;
    }
    __syncthreads();

    // bulk BCE sweep
    float loss = 0.f;
    for (int i = tid; i < tc * 8; i += 512) {
      float l = logitb[i];
      float gtv = gt[(size_t)(t0 + (i >> 3) + 1) * 256 + g * 8 + (i & 7)];
      float t1 = log1pf(__expf(-fabsf(l)));
      loss += gtv * (fmaxf(-l, 0.f) + t1) + (1.f - gtv) * (fmaxf(l, 0.f) + t1);
    }
    loss += __shfl_xor(loss, 1);
    loss += __shfl_xor(loss, 2);
    loss += __shfl_xor(loss, 4);
    loss += __shfl_xor(loss, 8);
    loss += __shfl_xor(loss, 16);
    loss += __shfl_xor(loss, 32);
    if (lane == 0) atomicAdd(out, loss);

    *(floatx4_t*)(h_ws + (size_t)(g * 8 + row) * 256 + colG) = ho;
  } else {
    // ================= gemm role: gi for next chunk =================
    const int gb = blockIdx.x - 32;
    const int bn = gb % 6, bb = gb / 6;  // n-tile 0..5, step bb < tgc
    const int n0 = bn * 128;
    __bf16(*As)[136] = (__bf16(*)[136])smem;            // Wih tile 128 rows
    __bf16(*Bs)[136] = (__bf16(*)[136])(smem + 34816);  // x tile 256 rows

    {
      const int r = tid >> 2, cc = (tid & 3) * 32;
      const floatx4_t* src =
          (const floatx4_t*)(Wih + (size_t)(n0 + r) * 128 + cc);
#pragma unroll
      for (int v = 0; v < 4; ++v) {
        floatx4_t a = src[v * 2], b = src[v * 2 + 1];
        bf16x8_t t;
#pragma unroll
        for (int j = 0; j < 4; ++j) {
          t[j] = (__bf16)a[j];
          t[4 + j] = (__bf16)b[j];
        }
        *(bf16x8_t*)&As[r][cc + v * 8] = t;
      }
      const int r2 = tid >> 1, c2 = (tid & 1) * 64;
      const floatx4_t* src2 =
          (const floatx4_t*)(x + ((size_t)(tg0 + bb) * 256 + r2) * 128 + c2);
#pragma unroll
      for (int v = 0; v < 8; ++v) {
        floatx4_t a = src2[v * 2], b = src2[v * 2 + 1];
        bf16x8_t t;
#pragma unroll
        for (int j = 0; j < 4; ++j) {
          t[j] = (__bf16)a[j];
          t[4 + j] = (__bf16)b[j];
        }
        *(bf16x8_t*)&Bs[r2][c2 + v * 8] = t;
      }
    }
    __syncthreads();

    const int wm = w >> 2, wb = w & 3;
    floatx4_t acc[4][4];
#pragma unroll
    for (int a = 0; a < 4; ++a)
#pragma unroll
      for (int b = 0; b < 4; ++b)
#pragma unroll
        for (int j = 0; j < 4; ++j) acc[a][b][j] = 0.f;

#pragma unroll
    for (int kk = 0; kk < 4; ++kk) {
      bf16x8_t af[4], bf[4];
#pragma unroll
      for (int mt = 0; mt < 4; ++mt)
        af[mt] = *(const bf16x8_t*)&As[wm * 64 + mt * 16 + nh][kk * 32 + q * 8];
#pragma unroll
      for (int nt = 0; nt < 4; ++nt)
        bf[nt] = *(const bf16x8_t*)&Bs[wb * 64 + nt * 16 + nh][kk * 32 + q * 8];
#pragma unroll
      for (int mt = 0; mt < 4; ++mt)
#pragma unroll
        for (int nt = 0; nt < 4; ++nt)
          acc[mt][nt] = __builtin_amdgcn_mfma_f32_16x16x32_bf16(
              af[mt], bf[nt], acc[mt][nt], 0, 0, 0);
    }

    u32x2_t* giw2 = (u32x2_t*)giw;
#pragma unroll
    for (int mt = 0; mt < 4; ++mt) {
      const int nn = n0 + wm * 64 + mt * 16 + q * 4;  // lane's 4 n's
      const int gate = nn >> 8;
      const float sc = (gate < 2) ? NL2E : (2.0f * NL2E);
      floatx4_t bias = *(const floatx4_t*)(bih + nn);
      if (gate < 2) {
        floatx4_t b2 = *(const floatx4_t*)(bhh + nn);
#pragma unroll
        for (int j = 0; j < 4; ++j) bias[j] += b2[j];
      }
      const int nc = nn & 255;
      const int w2 = nc >> 5;
      const int cgl = (nc & 31) >> 2;  // 0..7
#pragma unroll
      for (int nt = 0; nt < 4; ++nt) {
        const int b = wb * 64 + nt * 16 + nh;  // 0..255 within step
        const int row8 = b & 7, g32 = b >> 3;
        size_t U = (((size_t)bb * 32 + g32) * 3 + gate) * 512 + w2 * 64 +
                   cgl * 8 + row8;
        u32x2_t pv;
        pv.x = pack2bf((acc[mt][nt][0] + bias[0]) * sc,
                       (acc[mt][nt][1] + bias[1]) * sc);
        pv.y = pack2bf((acc[mt][nt][2] + bias[2]) * sc,
                       (acc[mt][nt][3] + bias[3]) * sc);
        giw2[U] = pv;
      }
    }
  }
}

// ---------------- host ----------------
extern "C" void kernel_launch(void* const* d_in, const int* in_sizes, int n_in,
                              void* d_out, int out_size, void* d_ws,
                              size_t ws_size, hipStream_t stream) {
  const float* x = (const float*)d_in[0];
  const float* gt = (const float*)d_in[1];
  const float* Wih = (const float*)d_in[2];
  const float* Whh = (const float*)d_in[3];
  const float* bih = (const float*)d_in[4];
  const float* bhh = (const float*)d_in[5];
  const float* Wdec = (const float*)d_in[6];
  const float* bdec = (const float*)d_in[7];
  float* out = (float*)d_out;

  char* ws = (char*)d_ws;
  char* Wq = ws;                        // 196608 B
  char* wdq = ws + 196608;              // 512 B
  float* h_ws = (float*)(ws + 197120);  // 262144 B
  u32* gi0 = (u32*)(ws + 524288);
  const size_t per_step = (size_t)256 * 768 * 2;  // 393216 B
  size_t avail = ws_size > 524288 ? ws_size - 524288 : per_step;
  size_t cap = avail / per_step;

  prep_kernel<<<256, 256, 0, stream>>>(Whh, Wdec, Wq, wdq, h_ws, out);

  if (cap >= 8) {
    // pipelined: double-buffered gi, gemm for chunk k+1 fused with rec k
    int Tc = (int)(cap / 2 < 64 ? cap / 2 : 64);
    u32* gi1 = (u32*)((char*)gi0 + (size_t)Tc * per_step);
    u32* bufs[2] = {gi0, gi1};
    const int nch = (511 + Tc - 1) / Tc;
    auto clen = [&](int k) {
      int s = k * Tc, L = 511 - s;
      return L > Tc ? Tc : L;
    };
    int tc0 = clen(0);
    fused_kernel<<<32 + 6 * tc0, 512, 0, stream>>>(
        Wq, wdq, x, Wih, bih, bhh, gt, bdec, h_ws, out, (const u32x2_t*)bufs[0],
        bufs[0], 0, 0, 0, tc0);
    for (int k = 0; k < nch; ++k) {
      const int tck = clen(k);
      const int tgn = (k + 1 < nch) ? clen(k + 1) : 0;
      fused_kernel<<<32 + 6 * tgn, 512, 0, stream>>>(
          Wq, wdq, x, Wih, bih, bhh, gt, bdec, h_ws, out,
          (const u32x2_t*)bufs[k & 1], bufs[(k + 1) & 1], k * Tc, tck,
          (k + 1) * Tc, tgn);
    }
  } else {
    // serial fallback: single gi buffer, gemm then rec per chunk
    int Tc = (int)(cap < 1 ? 1 : (cap > 511 ? 511 : cap));
    for (int t0 = 0; t0 < 511; t0 += Tc) {
      const int tck = (511 - t0 < Tc) ? (511 - t0) : Tc;
      fused_kernel<<<32 + 6 * tck, 512, 0, stream>>>(
          Wq, wdq, x, Wih, bih, bhh, gt, bdec, h_ws, out,
          (const u32x2_t*)gi0, gi0, 0, 0, t0, tck);
      fused_kernel<<<32, 512, 0, stream>>>(
          Wq, wdq, x, Wih, bih, bhh, gt, bdec, h_ws, out,
          (const u32x2_t*)gi0, gi0, t0, tck, 0, 0);
    }
  }
}

// Round 7
// 751.503 us; speedup vs baseline: 1.0163x; 1.0163x over previous
//
#include <hip/hip_runtime.h>
#include <hip/hip_bf16.h>

// CensorNet T=512,B=256,I=128,H=256 GRU scan + BCE decode.
// R7: unfused (fusion cost rec +0.4us/step in R5/R6). rec: 64 WGs x 4 rows,
// NO LDS transpose -- shfl_xor(8) redistributes s-halves so 32 lanes hold 4
// gate elems each straight from MFMA C-regs; h ping-pong XOR-swizzled
// (conflict-free b128); gi laid out per-lane-coalesced. gemm1: bf16-staged
// swizzled tiles, 2 WGs/CU, writes rec's gi layout directly.

typedef __bf16 bf16x8_t __attribute__((ext_vector_type(8)));
typedef float floatx4_t __attribute__((ext_vector_type(4)));
typedef int intx4_t __attribute__((ext_vector_type(4)));
typedef unsigned int u32;
typedef u32 u32x2_t __attribute__((ext_vector_type(2)));

#define SW 2032.0f
#define SH 127.0f
#define INV_S (1.0f / (127.0f * 2032.0f))
#define NL2E (-1.44269504088896f) /* -log2(e) */
#define CRZ (NL2E * INV_S)
#define CN (2.0f * NL2E * INV_S)

static __device__ inline u32 pack2bf(float a, float b) {
  __bf16 x = (__bf16)a, y = (__bf16)b;
  unsigned short ux = *(unsigned short*)&x, uy = *(unsigned short*)&y;
  return (u32)ux | ((u32)uy << 16);
}

// ------- prep: quantize W_hh/W_dec to i8, Wih->bf16, zero h_ws/out -------
__global__ void prep_kernel(const float* __restrict__ Whh,
                            const float* __restrict__ Wdec,
                            const float* __restrict__ Wih,
                            char* __restrict__ Wq, char* __restrict__ wdq,
                            __bf16* __restrict__ Wihb,
                            float* __restrict__ h_ws, float* __restrict__ out) {
  int idx = blockIdx.x * 256 + threadIdx.x;  // 65536 total
  for (int i = idx; i < 768 * 256; i += 65536) {
    int v = (int)rintf(Whh[i] * SW);
    v = v > 127 ? 127 : (v < -127 ? -127 : v);
    Wq[i] = (char)v;
  }
  if (idx < 256) {
    int v = (int)rintf(Wdec[idx] * SW);
    v = v > 127 ? 127 : (v < -127 ? -127 : v);
    wdq[idx] = (char)v;
  }
  for (int i = idx; i < 768 * 128; i += 65536) Wihb[i] = (__bf16)Wih[i];
  if (idx < 65536) h_ws[idx] = 0.f;
  if (idx == 0) out[0] = 0.f;
}

// ------- gemm1: gi = scale*(x @ Wih.T + biases), rec-native layout -------
// u32x2 unit = 4 bf16 (cols nn..nn+3). Unit index:
//   U = t*49152 + ((g64*8 + w)*3 + gate)*32 + q*8 + s*4 + r4
// where b = t*256 + g64*4 + r4, n = gate*256 + w*32 + s*16 + q*4 (+j).
// Pre-scaled: r,z: NL2E*(gi+bih+bhh); n: 2*NL2E*(gi+bih).
__global__ __launch_bounds__(256) void gemm1_kernel(
    const float* __restrict__ x,      // [512*256][128] fp32
    const __bf16* __restrict__ Wihb,  // [768][128] bf16
    const float* __restrict__ bih, const float* __restrict__ bhh,
    u32x2_t* __restrict__ gi, int t0) {
  __shared__ __align__(16) __bf16 As[128 * 128];  // swizzled 16B blocks
  __shared__ __align__(16) __bf16 Bs[128 * 128];

  const int tid = threadIdx.x;
  const int w = tid >> 6, lane = tid & 63;
  const int q = lane >> 4, nh = lane & 15;
  const int n0 = blockIdx.x * 128;  // 0..5
  const int b0 = blockIdx.y * 128;  // 0,128
  const int tl = blockIdx.z;        // local step

  {
    const int r = tid >> 1, half = tid & 1;
    const __bf16* asrc = Wihb + (size_t)(n0 + r) * 128 + half * 64;
#pragma unroll
    for (int v = 0; v < 8; ++v) {
      bf16x8_t t = *(const bf16x8_t*)(asrc + v * 8);
      const int bi = half * 8 + v;
      *(bf16x8_t*)&As[r * 128 + ((bi ^ (r & 7)) * 8)] = t;
    }
    const float* bsrc =
        x + ((size_t)(t0 + tl) * 256 + b0 + r) * 128 + half * 64;
#pragma unroll
    for (int v = 0; v < 8; ++v) {
      floatx4_t a = *(const floatx4_t*)(bsrc + v * 8);
      floatx4_t b = *(const floatx4_t*)(bsrc + v * 8 + 4);
      bf16x8_t t;
#pragma unroll
      for (int j = 0; j < 4; ++j) {
        t[j] = (__bf16)a[j];
        t[4 + j] = (__bf16)b[j];
      }
      const int bi = half * 8 + v;
      *(bf16x8_t*)&Bs[r * 128 + ((bi ^ (r & 7)) * 8)] = t;
    }
  }
  __syncthreads();

  const int wm = w >> 1, wn = w & 1;
  floatx4_t acc[4][4];
#pragma unroll
  for (int a = 0; a < 4; ++a)
#pragma unroll
    for (int b = 0; b < 4; ++b)
#pragma unroll
      for (int j = 0; j < 4; ++j) acc[a][b][j] = 0.f;

#pragma unroll
  for (int kk = 0; kk < 4; ++kk) {
    bf16x8_t af[4], bf[4];
#pragma unroll
    for (int mt = 0; mt < 4; ++mt) {
      const int r = wm * 64 + mt * 16 + nh;
      af[mt] = *(const bf16x8_t*)&As[r * 128 + (((kk * 4 + q) ^ (nh & 7)) * 8)];
    }
#pragma unroll
    for (int nt = 0; nt < 4; ++nt) {
      const int r = wn * 64 + nt * 16 + nh;
      bf[nt] = *(const bf16x8_t*)&Bs[r * 128 + (((kk * 4 + q) ^ (nh & 7)) * 8)];
    }
#pragma unroll
    for (int mt = 0; mt < 4; ++mt)
#pragma unroll
      for (int nt = 0; nt < 4; ++nt)
        acc[mt][nt] = __builtin_amdgcn_mfma_f32_16x16x32_bf16(
            af[mt], bf[nt], acc[mt][nt], 0, 0, 0);
  }

#pragma unroll
  for (int mt = 0; mt < 4; ++mt) {
    const int nn = n0 + wm * 64 + mt * 16 + q * 4;  // lane's 4 n's
    const int gate = nn >> 8;
    const float sc = (gate < 2) ? NL2E : (2.0f * NL2E);
    floatx4_t bias = *(const floatx4_t*)(bih + nn);
    if (gate < 2) {
      floatx4_t b2 = *(const floatx4_t*)(bhh + nn);
#pragma unroll
      for (int j = 0; j < 4; ++j) bias[j] += b2[j];
    }
    const int nc = nn & 255;
    const int w_r = nc >> 5, s_r = (nc >> 4) & 1, qr = (nc >> 2) & 3;
#pragma unroll
    for (int nt = 0; nt < 4; ++nt) {
      const int bb = b0 + wn * 64 + nt * 16 + nh;
      const int g64 = bb >> 2, r4 = bb & 3;
      size_t U = (size_t)tl * 49152 +
                 (((size_t)g64 * 8 + w_r) * 3 + gate) * 32 + qr * 8 + s_r * 4 +
                 r4;
      u32x2_t pv;
      pv.x = pack2bf((acc[mt][nt][0] + bias[0]) * sc,
                     (acc[mt][nt][1] + bias[1]) * sc);
      pv.y = pack2bf((acc[mt][nt][2] + bias[2]) * sc,
                     (acc[mt][nt][3] + bias[3]) * sc);
      gi[U] = pv;
    }
  }
}

// ------- rec: serial scan, i8 MFMA, shfl-redistributed gates -------------
__global__ __launch_bounds__(512, 2) void rec_kernel(
    const char* __restrict__ Wq,      // [768][256] i8
    const char* __restrict__ wdq,     // [256] i8
    const u32x2_t* __restrict__ gi,   // pre-scaled, rec-native layout
    const float* __restrict__ gt, const float* __restrict__ bdec,
    const float* __restrict__ bhh, float* __restrict__ h_ws,
    float* __restrict__ out, int t0, int tc) {
  __shared__ __align__(16) char hb[2][4][256];  // h i8 ping-pong, swizzled
  __shared__ float logitb[2048];                // per-step logits

  const int tid = threadIdx.x;
  const int w = tid >> 6, lane = tid & 63;
  const int q = lane >> 4, nh = lane & 15;
  const int g = blockIdx.x;        // batch rows g*4..g*4+3
  const int sel = nh >> 3;         // col half (gate phase)
  const int brow = nh & 3;         // batch row (gate phase)
  const int actv = !(nh & 4);      // 32 active gate lanes
  const int colb = w * 32 + sel * 16 + q * 4;  // lane's 4 gate cols

  // W_hh fragments (A-operand): wave w owns cols w*32..+31 per gate
  intx4_t wf[6][4];
#pragma unroll
  for (int c = 0; c < 3; ++c)
#pragma unroll
    for (int ss = 0; ss < 2; ++ss) {
      const int n = c * 256 + w * 32 + ss * 16 + nh;
#pragma unroll
      for (int kb = 0; kb < 4; ++kb)
        wf[c * 2 + ss][kb] =
            *(const intx4_t*)(Wq + (size_t)n * 256 + kb * 64 + q * 16);
    }
  intx4_t wdf[4];
#pragma unroll
  for (int kb = 0; kb < 4; ++kb) {
    intx4_t z = {0, 0, 0, 0};
    intx4_t v = *(const intx4_t*)(wdq + kb * 64 + q * 16);
    wdf[kb] = (nh == 0) ? v : z;  // A-row 0 = Wdec
  }
  const floatx4_t bhv = *(const floatx4_t*)(bhh + 512 + colb);
  floatx4_t bnv;
#pragma unroll
  for (int j = 0; j < 4; ++j) bnv[j] = 2.0f * NL2E * bhv[j];
  const float bdec0 = bdec[0];

  // stage initial h (quantized i8, swizzled blocks)
  if (tid < 256) {
    const int r = tid >> 6, c0 = (tid & 63) * 4;
    u32 p = 0;
#pragma unroll
    for (int j = 0; j < 4; ++j) {
      int a = (int)rintf(h_ws[(size_t)(g * 4 + r) * 256 + c0 + j] * SH);
      a = a > 127 ? 127 : (a < -127 ? -127 : a);
      p |= ((u32)(a & 255)) << (8 * j);
    }
    const int bi = c0 >> 4;
    *(u32*)&hb[0][r][((bi ^ (r * 4)) * 16) + (c0 & 12)] = p;
  }
  floatx4_t ho =
      *(const floatx4_t*)(h_ws + (size_t)(g * 4 + brow) * 256 + colb);
  __syncthreads();

  // gi: each lane loads exactly its own 3 gates (8 B each), coalesced
  const size_t u0 = ((size_t)g * 8 + w) * 96 + (q * 8 + sel * 4 + brow);
  u32x2_t gcur[3], gnxt[3];
#pragma unroll
  for (int c = 0; c < 3; ++c) gcur[c] = gi[u0 + c * 32];

#pragma unroll 1
  for (int t = 0; t < tc; ++t) {
    const int pb = t & 1;
    {
      const int tp = (t + 1 < tc) ? t + 1 : t;
      const size_t u = (size_t)tp * 49152 + u0;
#pragma unroll
      for (int c = 0; c < 3; ++c) gnxt[c] = gi[u + c * 32];
    }

    intx4_t hbf[4];
#pragma unroll
    for (int kb = 0; kb < 4; ++kb) {
      intx4_t z = {0, 0, 0, 0};
      hbf[kb] = z;
    }
    if (nh < 4) {
#pragma unroll
      for (int kb = 0; kb < 4; ++kb)
        hbf[kb] =
            *(const intx4_t*)&hb[pb][nh][(((kb * 4 + q) ^ (nh * 4)) & 15) * 16];
    }

    intx4_t acc[6], facc;
#pragma unroll
    for (int cs = 0; cs < 6; ++cs)
#pragma unroll
      for (int j = 0; j < 4; ++j) acc[cs][j] = 0;
#pragma unroll
    for (int j = 0; j < 4; ++j) facc[j] = 0;

#pragma unroll
    for (int kb = 0; kb < 4; ++kb) {
#pragma unroll
      for (int cs = 0; cs < 6; ++cs)
        acc[cs] = __builtin_amdgcn_mfma_i32_16x16x64_i8(wf[cs][kb], hbf[kb],
                                                        acc[cs], 0, 0, 0);
      if (w == 0)
        facc = __builtin_amdgcn_mfma_i32_16x16x64_i8(wdf[kb], hbf[kb], facc,
                                                     0, 0, 0);
    }

    // redistribute s=1 halves to lanes nh>=8 (j stays lane-local)
    intx4_t aR, aZ, aN;
#pragma unroll
    for (int j = 0; j < 4; ++j) {
      int r1 = __shfl_xor(acc[1][j], 8);
      int z1 = __shfl_xor(acc[3][j], 8);
      int n1 = __shfl_xor(acc[5][j], 8);
      aR[j] = sel ? r1 : acc[0][j];
      aZ[j] = sel ? z1 : acc[2][j];
      aN[j] = sel ? n1 : acc[4][j];
    }

    float gr[4], gz[4], gn[4];
    gr[0] = __uint_as_float(gcur[0].x << 16);
    gr[1] = __uint_as_float(gcur[0].x & 0xffff0000u);
    gr[2] = __uint_as_float(gcur[0].y << 16);
    gr[3] = __uint_as_float(gcur[0].y & 0xffff0000u);
    gz[0] = __uint_as_float(gcur[1].x << 16);
    gz[1] = __uint_as_float(gcur[1].x & 0xffff0000u);
    gz[2] = __uint_as_float(gcur[1].y << 16);
    gz[3] = __uint_as_float(gcur[1].y & 0xffff0000u);
    gn[0] = __uint_as_float(gcur[2].x << 16);
    gn[1] = __uint_as_float(gcur[2].x & 0xffff0000u);
    gn[2] = __uint_as_float(gcur[2].y << 16);
    gn[3] = __uint_as_float(gcur[2].y & 0xffff0000u);

    u32 pk = 0;
#pragma unroll
    for (int j = 0; j < 4; ++j) {
      float rr = __builtin_amdgcn_rcpf(
          1.f +
          __builtin_amdgcn_exp2f(__builtin_fmaf((float)aR[j], CRZ, gr[j])));
      float zz = __builtin_amdgcn_rcpf(
          1.f +
          __builtin_amdgcn_exp2f(__builtin_fmaf((float)aZ[j], CRZ, gz[j])));
      float hn2 = __builtin_fmaf((float)aN[j], CN, bnv[j]);
      float tv = 2.f * __builtin_amdgcn_rcpf(
                           1.f + __builtin_amdgcn_exp2f(
                                     __builtin_fmaf(rr, hn2, gn[j]))) -
                 1.f;
      float hnew = tv + zz * (ho[j] - tv);
      ho[j] = hnew;
      int hq = (int)rintf(hnew * SH);  // |h|<1 -> no clamp
      pk |= ((u32)(hq & 255)) << (8 * j);
    }
    if (actv)
      *(u32*)&hb[1 - pb][brow][(((w * 2 + sel) ^ (brow * 4)) * 16) + q * 4] =
          pk;

    if (w == 0 && q == 0 && nh < 4 && t >= 1)
      logitb[(t - 1) * 4 + nh] = (float)facc[0] * INV_S + bdec0;
    __syncthreads();
#pragma unroll
    for (int c = 0; c < 3; ++c) gcur[c] = gnxt[c];
  }

  // tail decode of final h
  if (w == 0) {
    intx4_t hbf2[4], fac2;
#pragma unroll
    for (int kb = 0; kb < 4; ++kb) {
      intx4_t z = {0, 0, 0, 0};
      hbf2[kb] = z;
    }
    if (nh < 4) {
#pragma unroll
      for (int kb = 0; kb < 4; ++kb)
        hbf2[kb] = *(const intx4_t*)&hb[tc & 1][nh]
                                      [(((kb * 4 + q) ^ (nh * 4)) & 15) * 16];
    }
#pragma unroll
    for (int j = 0; j < 4; ++j) fac2[j] = 0;
#pragma unroll
    for (int kb = 0; kb < 4; ++kb)
      fac2 = __builtin_amdgcn_mfma_i32_16x16x64_i8(wdf[kb], hbf2[kb], fac2, 0,
                                                   0, 0);
    if (q == 0 && nh < 4)
      logitb[(tc - 1) * 4 + nh] = (float)fac2[0] * INV_S + bdec0;
  }
  __syncthreads();

  // bulk BCE sweep
  float loss = 0.f;
  for (int i = tid; i < tc * 4; i += 512) {
    float l = logitb[i];
    float gtv = gt[(size_t)(t0 + (i >> 2) + 1) * 256 + g * 4 + (i & 3)];
    float t1 = log1pf(__expf(-fabsf(l)));
    loss += gtv * (fmaxf(-l, 0.f) + t1) + (1.f - gtv) * (fmaxf(l, 0.f) + t1);
  }
  loss += __shfl_xor(loss, 1);
  loss += __shfl_xor(loss, 2);
  loss += __shfl_xor(loss, 4);
  loss += __shfl_xor(loss, 8);
  loss += __shfl_xor(loss, 16);
  loss += __shfl_xor(loss, 32);
  if (lane == 0) atomicAdd(out, loss);

  // persist h for next chunk (active lanes only)
  if (actv)
    *(floatx4_t*)(h_ws + (size_t)(g * 4 + brow) * 256 + colb) = ho;
}

// ---------------- host ----------------
extern "C" void kernel_launch(void* const* d_in, const int* in_sizes, int n_in,
                              void* d_out, int out_size, void* d_ws,
                              size_t ws_size, hipStream_t stream) {
  const float* x = (const float*)d_in[0];     // [512,256,128]
  const float* gt = (const float*)d_in[1];    // [512,256,1]
  const float* Wih = (const float*)d_in[2];   // [768,128]
  const float* Whh = (const float*)d_in[3];   // [768,256]
  const float* bih = (const float*)d_in[4];   // [768]
  const float* bhh = (const float*)d_in[5];   // [768]
  const float* Wdec = (const float*)d_in[6];  // [1,256]
  const float* bdec = (const float*)d_in[7];  // [1]
  float* out = (float*)d_out;

  char* ws = (char*)d_ws;
  char* Wq = ws;                          // 196608
  char* wdq = ws + 196608;                // 1024 (256 used)
  float* h_ws = (float*)(ws + 197632);    // 262144
  __bf16* Wihb = (__bf16*)(ws + 459776);  // 196608
  u32x2_t* gi = (u32x2_t*)(ws + 656384);  // Tc * 393216 B
  const size_t per_step = 393216;
  size_t avail = ws_size > 656384 ? ws_size - 656384 : per_step;
  int Tc = (int)(avail / per_step);
  if (Tc < 1) Tc = 1;
  if (Tc > 511) Tc = 511;

  prep_kernel<<<256, 256, 0, stream>>>(Whh, Wdec, Wih, Wq, wdq, Wihb, h_ws,
                                       out);
  for (int t0 = 0; t0 < 511; t0 += Tc) {
    const int tck = (511 - t0 < Tc) ? (511 - t0) : Tc;
    gemm1_kernel<<<dim3(6, 2, tck), 256, 0, stream>>>(x, Wihb, bih, bhh, gi,
                                                      t0);
    rec_kernel<<<64, 512, 0, stream>>>(Wq, wdq, gi, gt, bdec, bhh, h_ws, out,
                                       t0, tck);
  }
}